// Round 2
// baseline (28.777 us; speedup 1.0000x reference)
//
#include <hip/hip_runtime.h>

#define NSEQ 4096
#define DIM  256
#define WIN  128
#define BATCH 4

typedef __bf16 bf16x8 __attribute__((ext_vector_type(8)));
typedef float  f32x4  __attribute__((ext_vector_type(4)));

__device__ __forceinline__ unsigned short f2bf(float f) {
    unsigned u = __builtin_bit_cast(unsigned, f);
    u += 0x7fffu + ((u >> 16) & 1u);   // RNE
    return (unsigned short)(u >> 16);
}

// element offset in subtiled LDS layout [j>>2][d>>4][j&3][d&15]
__device__ __forceinline__ int sub_off(int j, int d) {
    return (((j >> 2) * 16 + (d >> 4)) << 6) + ((j & 3) << 4) + (d & 15);
}

#define VJT_STRIDE 40   // [d][j] rows padded 32->40 elements: 80B rows, 16B-aligned b128 reads

__global__ __launch_bounds__(256, 2)
void sp_kernel(const float* __restrict__ val,
               const float* __restrict__ state,
               float* __restrict__ out) {
    __shared__ unsigned short vi_s[32 * 256];        // 16 KB, subtiled bf16 (scores A)
    __shared__ unsigned short vj_s[32 * 256];        // 16 KB, subtiled bf16 (scores B)
    __shared__ unsigned short vjT_s[256 * VJT_STRIDE]; // 20 KB, Vj^T [d][j] (PV B)
    __shared__ unsigned short E_s[32 * 56];          // edges, row stride 56 (16B aligned)
    __shared__ float ds_part[4][16];

    const int bx = blockIdx.x;
    const int b  = bx >> 7;            // 128 row-tiles per batch
    const int r0 = (bx & 127) << 5;    // BR = 32

    const int t   = threadIdx.x;
    const int w   = t >> 6;
    const int l   = t & 63;
    const int l15 = l & 15;
    const int l4  = l >> 4;
    const int mt  = w >> 1;            // score row-tile  (0..1)
    const int jt  = w & 1;             // score col-tile  (0..1)

    const float* valb = val + ((size_t)b * NSEQ) * DIM;
    const float* stb  = state + (size_t)b * NSEQ;
    float* out_state  = out + (size_t)b * NSEQ;
    float* out_val    = out + (size_t)BATCH * NSEQ + ((size_t)b * NSEQ) * DIM;

    // ---- stage Vi rows [r0, r0+32) : f32 -> bf16 subtiled ----
    {
        const float* src = valb + (size_t)r0 * DIM;
        #pragma unroll
        for (int p = 0; p < 8; ++p) {
            int jl = (w << 2) + l4 + ((p & 1) << 4);
            int d0 = (l15 << 2) + ((p >> 1) << 6);
            float4 v = *reinterpret_cast<const float4*>(src + jl * DIM + d0);
            ushort4 h;
            h.x = f2bf(v.x); h.y = f2bf(v.y); h.z = f2bf(v.z); h.w = f2bf(v.w);
            *reinterpret_cast<ushort4*>(&vi_s[sub_off(jl, d0)]) = h;
        }
    }

    float dsacc[4] = {0.f, 0.f, 0.f, 0.f};
    f32x4 accpv[2][4];
    #pragma unroll
    for (int m2 = 0; m2 < 2; ++m2)
        #pragma unroll
        for (int tt = 0; tt < 4; ++tt)
            accpv[m2][tt] = (f32x4){0.f, 0.f, 0.f, 0.f};

    const int jb_start = (r0 >= WIN) ? (r0 - WIN) : 0;

    for (int jb = jb_start; jb <= r0; jb += 32) {
        // ---- stage Vj tile: subtiled copy (scores B) + transposed copy (PV B) ----
        {
            const float* src = valb + (size_t)jb * DIM;
            #pragma unroll
            for (int p = 0; p < 8; ++p) {
                int jl = (w << 2) + l4 + ((p & 1) << 4);
                int d0 = (l15 << 2) + ((p >> 1) << 6);
                float4 v = *reinterpret_cast<const float4*>(src + jl * DIM + d0);
                ushort4 h;
                h.x = f2bf(v.x); h.y = f2bf(v.y); h.z = f2bf(v.z); h.w = f2bf(v.w);
                *reinterpret_cast<ushort4*>(&vj_s[sub_off(jl, d0)]) = h;
                vjT_s[(d0 + 0) * VJT_STRIDE + jl] = h.x;
                vjT_s[(d0 + 1) * VJT_STRIDE + jl] = h.y;
                vjT_s[(d0 + 2) * VJT_STRIDE + jl] = h.z;
                vjT_s[(d0 + 3) * VJT_STRIDE + jl] = h.w;
            }
        }
        __syncthreads();

        // ---- scores: S(16x16 per wave) = Vi x Vj^T, K = 256 ----
        f32x4 acc = (f32x4){0.f, 0.f, 0.f, 0.f};
        const int il = (mt << 4) + l15;
        const int jl = (jt << 4) + l15;
        #pragma unroll
        for (int ks = 0; ks < 8; ++ks) {
            const int k = (l4 << 3) + (ks << 5);
            bf16x8 af  = *reinterpret_cast<const bf16x8*>(&vi_s[sub_off(il, k)]);
            bf16x8 bf_ = *reinterpret_cast<const bf16x8*>(&vj_s[sub_off(jl, k)]);
            acc = __builtin_amdgcn_mfma_f32_16x16x32_bf16(af, bf_, acc, 0, 0, 0);
        }

        // ---- edges: scale, softsign, mask; accumulate delta_state; write E tile ----
        const int jg = jb + jl;                  // global j for this lane's column
        const float stv = stb[jg];
        const int ib = r0 + (mt << 4) + (l4 << 2);
        #pragma unroll
        for (int r = 0; r < 4; ++r) {
            float s = acc[r] * 0.0625f;          // / sqrt(256)
            float e = s / (1.0f + fabsf(s));
            const int ig = ib + r;
            if (jg > ig || jg < ig - WIN) e = 0.0f;
            dsacc[r] += e * stv;
            E_s[((mt << 4) + (l4 << 2) + r) * 56 + (jt << 4) + l15] = f2bf(e);
        }
        __syncthreads();

        // ---- PV: delta_val(32x256) += E(32x32) x Vj(32x256); wave owns d-cols [64w, 64w+64) ----
        // Both operands loaded k-contiguous (8 along j) -> any internal k-permutation cancels.
        bf16x8 ef0 = *reinterpret_cast<const bf16x8*>(&E_s[l15 * 56 + (l4 << 3)]);
        bf16x8 ef1 = *reinterpret_cast<const bf16x8*>(&E_s[(16 + l15) * 56 + (l4 << 3)]);
        #pragma unroll
        for (int tt = 0; tt < 4; ++tt) {
            const int nt = (w << 2) + tt;        // d-subtile index 0..15
            const int d  = (nt << 4) + l15;      // this lane's output column
            bf16x8 bfr = *reinterpret_cast<const bf16x8*>(&vjT_s[d * VJT_STRIDE + (l4 << 3)]);
            accpv[0][tt] = __builtin_amdgcn_mfma_f32_16x16x32_bf16(ef0, bfr, accpv[0][tt], 0, 0, 0);
            accpv[1][tt] = __builtin_amdgcn_mfma_f32_16x16x32_bf16(ef1, bfr, accpv[1][tt], 0, 0, 0);
        }
        __syncthreads();   // protect vj_s / vjT_s / E_s before next tile
    }

    // ---- delta_state: reduce over the 16 j-lanes, combine 2 col-half waves via LDS ----
    #pragma unroll
    for (int m = 1; m <= 8; m <<= 1) {
        #pragma unroll
        for (int r = 0; r < 4; ++r)
            dsacc[r] += __shfl_xor(dsacc[r], m, 64);
    }
    if (l15 == 0) {
        #pragma unroll
        for (int r = 0; r < 4; ++r)
            ds_part[w][(l4 << 2) + r] = dsacc[r];
    }
    __syncthreads();
    if (t < 32) {
        const int m2 = t >> 4;
        out_state[r0 + t] = ds_part[(m2 << 1)][t & 15] + ds_part[(m2 << 1) + 1][t & 15];
    }

    // ---- delta_val epilogue: C layout col=lane&15, row=(lane>>4)*4+r (m89-verified) ----
    #pragma unroll
    for (int m2 = 0; m2 < 2; ++m2) {
        #pragma unroll
        for (int tt = 0; tt < 4; ++tt) {
            const int d = (w << 6) + (tt << 4) + l15;
            #pragma unroll
            for (int r = 0; r < 4; ++r) {
                const int ig = r0 + (m2 << 4) + (l4 << 2) + r;
                out_val[(size_t)ig * DIM + d] = accpv[m2][tt][r];
            }
        }
    }
}

extern "C" void kernel_launch(void* const* d_in, const int* in_sizes, int n_in,
                              void* d_out, int out_size, void* d_ws, size_t ws_size,
                              hipStream_t stream) {
    const float* val   = (const float*)d_in[0];
    const float* state = (const float*)d_in[1];
    float* out = (float*)d_out;
    dim3 grid(BATCH * (NSEQ / 32));   // 512 blocks
    dim3 block(256);
    sp_kernel<<<grid, block, 0, stream>>>(val, state, out);
}